// Round 6
// baseline (529.542 us; speedup 1.0000x reference)
//
#include <hip/hip_runtime.h>

// GraphLinear: out[b,n,o] = sum_m g[n,m] * (sum_i input[b,m,i]*W[type[m],o,i]) + bias[o]
// B=16384, N=128, DIN=DOUT=64, T=16.
// prep: bf16-convert weight/g; pack groups of 4 same-type m's into 2 ints each.
// main: BT=4 b-rows/block, 512 threads (8 waves), 64 KiB LDS, 2 blocks/CU.
//   Stage 1: grouped 16x16x32 MFMA (4 m x 4 b share one W[t]); scalar metadata;
//            depth-1 prefetch of BOTH input (raw f32, cvt deferred) and weights.
//   Stage 2: 32x32x16 MFMA, A=h^T (hoisted+pinned in regs) B=g^T; dwordx4 stores.

#define NN    128
#define DI    64
#define DOUT  64
#define BT    4
#define TT    16
#define MAXG4 64

typedef __attribute__((ext_vector_type(4)))  float f32x4;
typedef __attribute__((ext_vector_type(16))) float f32x16;
typedef __attribute__((ext_vector_type(8)))  short bf16x8;

__device__ __forceinline__ short f2bf(float f) {
    unsigned u = __builtin_bit_cast(unsigned, f);
    u += 0x7FFFu + ((u >> 16) & 1u);   // round-to-nearest-even
    return (short)(u >> 16);
}

__device__ __forceinline__ bf16x8 cvt8(f32x4 a, f32x4 b) {
    bf16x8 r;
    r[0] = f2bf(a[0]); r[1] = f2bf(a[1]); r[2] = f2bf(a[2]); r[3] = f2bf(a[3]);
    r[4] = f2bf(b[0]); r[5] = f2bf(b[1]); r[6] = f2bf(b[2]); r[7] = f2bf(b[3]);
    return r;
}

// Device-global scratch (rewritten every launch by prep_kernel; deterministic).
__device__ short d_wb[TT * DOUT * DI];   // bf16 weight [t][o][i], 128 KB (L2-hot)
__device__ short d_gb[NN * NN];          // bf16 g [n][m], 32 KB (L1-resident)
__device__ int   d_gp[MAXG4 * 2];        // packed groups: {m0|m1<<8|m2<<16|m3<<24, type}
__device__ int   d_gcount[1];            // padded group count (multiple of 8)

__global__ void prep_kernel(const float* __restrict__ weight,
                            const float* __restrict__ g,
                            const int*   __restrict__ ntype) {
    const int tid    = blockIdx.x * blockDim.x + threadIdx.x;
    const int stride = gridDim.x * blockDim.x;
    for (int i = tid; i < TT * DOUT * DI; i += stride) d_wb[i] = f2bf(weight[i]);
    for (int i = tid; i < NN * NN; i += stride)        d_gb[i] = f2bf(g[i]);
    if (tid == 0) {
        int G = 0;
        for (int t = 0; t < TT; ++t) {
            int mbuf[4]; int cur = 0;
            for (int m = 0; m < NN; ++m) {
                if (ntype[m] == t) {
                    mbuf[cur++] = m;
                    if (cur == 4) {
                        d_gp[G * 2]     = mbuf[0] | (mbuf[1] << 8) | (mbuf[2] << 16) | (mbuf[3] << 24);
                        d_gp[G * 2 + 1] = t;
                        ++G; cur = 0;
                    }
                }
            }
            if (cur > 0) {
                int pk = 0;
                for (int k = 0; k < 4; ++k) pk |= ((k < cur) ? mbuf[k] : 0xFF) << (8 * k);
                d_gp[G * 2] = pk; d_gp[G * 2 + 1] = t; ++G;
            }
        }
        while (G & 7) { d_gp[G * 2] = (int)0xFFFFFFFF; d_gp[G * 2 + 1] = 0; ++G; }
        d_gcount[0] = G;   // <= 48, multiple of 8
    }
}

__global__ __launch_bounds__(512, 4)
void graph_linear_main(const float* __restrict__ input,   // [B,128,64] f32
                       const float* __restrict__ bias,    // [64] f32
                       float* __restrict__ out)           // [B,128,64] f32
{
    // h: [b=4][o=64][m=128] bf16 = 64 KiB; m XOR-swizzled by ((o&7)<<3) (short units).
    __shared__ short hbuf[BT * DOUT * NN];

    const int tid  = threadIdx.x;
    const int lane = tid & 63;
    const int wave = tid >> 6;        // 0..7
    const int lo   = lane & 15;
    const int hi   = lane >> 4;       // 0..3
    const int b0   = blockIdx.x * BT;

    // ---------------- stage 1: grouped MFMA, A rows r = mi*4 + bi ----------------
    const int iters = d_gcount[0] >> 3;    // groups padded to multiple of 8
    const int sl    = lo >> 2;             // this lane's A-row m-slot
    const float* const inpb = input + (size_t)(b0 + (lo & 3)) * NN * DI;

    int giu = __builtin_amdgcn_readfirstlane(wave) * 2;
    int pk  = d_gp[giu];
    int tt  = d_gp[giu + 1];

    f32x4  ar[4];    // raw f32 input prefetch (cvt deferred to consumption)
    bf16x8 w[8];     // weight prefetch (already bf16 in d_wb)
    {
        const int mA  = (pk >> (8 * sl)) & 0xFF;
        const int mAe = (mA == 0xFF) ? (pk & 0x7F) : mA;   // alias slot-0 row (L2 hit)
        const float* ip = inpb + mAe * DI + hi * 8;
        ar[0] = *(const f32x4*)(ip);
        ar[1] = *(const f32x4*)(ip + 4);
        ar[2] = *(const f32x4*)(ip + 32);
        ar[3] = *(const f32x4*)(ip + 36);
        const short* wr = d_wb + tt * (DOUT * DI);
#pragma unroll
        for (int ot = 0; ot < 4; ++ot) {
            w[2*ot]   = *(const bf16x8*)(wr + (ot*16 + lo) * DI + hi * 8);
            w[2*ot+1] = *(const bf16x8*)(wr + (ot*16 + lo) * DI + 32 + hi * 8);
        }
    }

    for (int it = 0; it < iters; ++it) {
        const int pk_c = pk;
        // convert previously-prefetched input (data already arrived; VALU only)
        const bf16x8 a0c = cvt8(ar[0], ar[1]);   // k = 0..31
        const bf16x8 a1c = cvt8(ar[2], ar[3]);   // k = 32..63
        bf16x8 wc[8];
#pragma unroll
        for (int q = 0; q < 8; ++q) wc[q] = w[q];

        // issue next group's prefetch (12 independent VMEM, no waits here)
        if (it + 1 < iters) {
            giu = __builtin_amdgcn_readfirstlane((it + 1) * 8 + wave) * 2;
            pk  = d_gp[giu];
            tt  = d_gp[giu + 1];
            const int mA  = (pk >> (8 * sl)) & 0xFF;
            const int mAe = (mA == 0xFF) ? (pk & 0x7F) : mA;
            const float* ip = inpb + mAe * DI + hi * 8;
            ar[0] = *(const f32x4*)(ip);
            ar[1] = *(const f32x4*)(ip + 4);
            ar[2] = *(const f32x4*)(ip + 32);
            ar[3] = *(const f32x4*)(ip + 36);
            const short* wr = d_wb + tt * (DOUT * DI);
#pragma unroll
            for (int ot = 0; ot < 4; ++ot) {
                w[2*ot]   = *(const bf16x8*)(wr + (ot*16 + lo) * DI + hi * 8);
                w[2*ot+1] = *(const bf16x8*)(wr + (ot*16 + lo) * DI + 32 + hi * 8);
            }
        }

        // MFMAs on current group (consume a0c/a1c/wc — loaded an iteration ago)
        f32x4 hacc[4];
#pragma unroll
        for (int ot = 0; ot < 4; ++ot) hacc[ot] = 0.0f;
#pragma unroll
        for (int ot = 0; ot < 4; ++ot) {
            hacc[ot] = __builtin_amdgcn_mfma_f32_16x16x32_bf16(a0c, wc[2*ot],   hacc[ot], 0, 0, 0);
            hacc[ot] = __builtin_amdgcn_mfma_f32_16x16x32_bf16(a1c, wc[2*ot+1], hacc[ot], 0, 0, 0);
        }
        // D: col(o)=lane&15, row r=hi*4+j -> m-slot=hi, b=j
        const int mS = (pk_c >> (8 * hi)) & 0xFF;
        if (mS != 0xFF) {
#pragma unroll
            for (int ot = 0; ot < 4; ++ot) {
                const int o = ot * 16 + lo;
                const int p = mS ^ ((o & 7) << 3);
#pragma unroll
                for (int j = 0; j < 4; ++j)
                    hbuf[(j * DOUT + o) * NN + p] = f2bf(hacc[ot][j]);
            }
        }
    }
    __syncthreads();

    // ---------------- stage 2: 32x32x16, wave -> (bi = w>>1, nh = w&1) ----------------
    const int bi  = wave >> 1;
    const int nh  = wave & 1;
    const int l31 = lane & 31;
    const int l5  = lane >> 5;     // 0/1
    const short* hrow = hbuf + bi * (DOUT * NN);
    const size_t outb = (size_t)(b0 + bi) * NN;

#pragma unroll
    for (int oT = 0; oT < 2; ++oT) {
        // A-frags: A[o][m], o = oT*32 + l31, m = kc*16 + l5*8 + e  (8 frags, 32 VGPR)
        const int o   = oT * 32 + l31;
        const int swz = (o & 7) << 3;
        bf16x8 ha[8];
#pragma unroll
        for (int kc = 0; kc < 8; ++kc)
            ha[kc] = *(const bf16x8*)&hrow[o * NN + ((kc * 16 + l5 * 8) ^ swz)];
        // Pin ha in registers: memory clobber makes LDS re-read illegal,
        // so the compiler must keep the 8 fragments live across both n-tiles.
        asm volatile("" ::: "memory");

#pragma unroll
        for (int nT = 0; nT < 2; ++nT) {
            const int n = nh * 64 + nT * 32 + l31;    // B-frag col = n
            // init acc from bias: acc reg r -> o_r = oT*32 + (r>>2)*8 + l5*4 + (r&3)
            f32x16 acc;
#pragma unroll
            for (int q = 0; q < 4; ++q) {
                const f32x4 bq = *(const f32x4*)(bias + oT * 32 + q * 8 + l5 * 4);
#pragma unroll
                for (int j = 0; j < 4; ++j) acc[q * 4 + j] = bq[j];
            }
#pragma unroll
            for (int kc = 0; kc < 8; ++kc) {
                const bf16x8 gb = *(const bf16x8*)(d_gb + n * NN + kc * 16 + l5 * 8);
                acc = __builtin_amdgcn_mfma_f32_32x32x16_bf16(ha[kc], gb, acc, 0, 0, 0);
            }
            // D: col=n, row o = oT*32 + (reg>>2)*8 + (lane>>5)*4 + (reg&3)
            //   -> each reg-quad = 4 consecutive o => contiguous dwordx4
#pragma unroll
            for (int q = 0; q < 4; ++q) {
                f32x4 v;
                v[0] = acc[q*4+0]; v[1] = acc[q*4+1]; v[2] = acc[q*4+2]; v[3] = acc[q*4+3];
                *(f32x4*)&out[(outb + n) * DOUT + oT * 32 + q * 8 + l5 * 4] = v;
            }
        }
    }
}

extern "C" void kernel_launch(void* const* d_in, const int* in_sizes, int n_in,
                              void* d_out, int out_size, void* d_ws, size_t ws_size,
                              hipStream_t stream) {
    const float* input  = (const float*)d_in[0];
    const float* g      = (const float*)d_in[1];
    const float* weight = (const float*)d_in[2];
    const float* bias   = (const float*)d_in[3];
    const int*   ntype  = (const int*)d_in[4];
    float* out = (float*)d_out;

    const int B = in_sizes[0] / (NN * DI);   // 16384

    hipLaunchKernelGGL(prep_kernel, dim3(32), dim3(256), 0, stream, weight, g, ntype);
    hipLaunchKernelGGL(graph_linear_main, dim3(B / BT), dim3(512), 0, stream,
                       input, bias, out);
}

// Round 7
// 492.203 us; speedup vs baseline: 1.0759x; 1.0759x over previous
//
#include <hip/hip_runtime.h>

// GraphLinear: out[b,n,o] = sum_m g[n,m] * (sum_i input[b,m,i]*W[type[m],o,i]) + bias[o]
// B=16384, N=128, DIN=DOUT=64, T=16.
// prep: bf16-convert weight/g; pack groups of 4 same-type m's; pad to EXACTLY 48 groups
//       so the main kernel's stage-1 loop has a compile-time trip count (6 per wave).
// main: BT=4 b-rows/block, 512 threads (8 waves), 64 KiB LDS, 2 blocks/CU.
//   Stage 1: fully-unrolled 6 iterations of grouped 16x16x32 MFMA (4 m x 4 b share W[t]).
//            NO manual prefetch - straight-line code lets the compiler software-pipeline
//            (runtime trip counts + branchy prefetch provably defeat it: R4-R6, VGPR~60).
//   Stage 2: round-5 measured-best: streamed 16x16x32, A=h^T B=g^T, dwordx4 stores.

#define NN    128
#define DI    64
#define DOUT  64
#define BT    4
#define TT    16
#define NG    48   // padded group count, compile-time

typedef __attribute__((ext_vector_type(4))) float f32x4;
typedef __attribute__((ext_vector_type(8))) short bf16x8;

__device__ __forceinline__ short f2bf(float f) {
    unsigned u = __builtin_bit_cast(unsigned, f);
    u += 0x7FFFu + ((u >> 16) & 1u);   // round-to-nearest-even
    return (short)(u >> 16);
}

__device__ __forceinline__ bf16x8 cvt8(f32x4 a, f32x4 b) {
    bf16x8 r;
    r[0] = f2bf(a[0]); r[1] = f2bf(a[1]); r[2] = f2bf(a[2]); r[3] = f2bf(a[3]);
    r[4] = f2bf(b[0]); r[5] = f2bf(b[1]); r[6] = f2bf(b[2]); r[7] = f2bf(b[3]);
    return r;
}

// Device-global scratch (rewritten every launch by prep_kernel; deterministic).
__device__ short d_wb[TT * DOUT * DI];   // bf16 weight [t][o][i], 128 KB (L2-hot)
__device__ short d_gb[NN * NN];          // bf16 g [n][m], 32 KB
__device__ int   d_gp[NG * 2];           // packed groups: {m0|m1<<8|m2<<16|m3<<24, type}

__global__ void prep_kernel(const float* __restrict__ weight,
                            const float* __restrict__ g,
                            const int*   __restrict__ ntype) {
    const int tid    = blockIdx.x * blockDim.x + threadIdx.x;
    const int stride = gridDim.x * blockDim.x;
    for (int i = tid; i < TT * DOUT * DI; i += stride) d_wb[i] = f2bf(weight[i]);
    for (int i = tid; i < NN * NN; i += stride)        d_gb[i] = f2bf(g[i]);
    if (tid == 0) {
        int G = 0;
        for (int t = 0; t < TT; ++t) {
            int mbuf[4]; int cur = 0;
            for (int m = 0; m < NN; ++m) {
                if (ntype[m] == t) {
                    mbuf[cur++] = m;
                    if (cur == 4) {
                        d_gp[G * 2]     = mbuf[0] | (mbuf[1] << 8) | (mbuf[2] << 16) | (mbuf[3] << 24);
                        d_gp[G * 2 + 1] = t;
                        ++G; cur = 0;
                    }
                }
            }
            if (cur > 0) {
                int pk = 0;
                for (int k = 0; k < 4; ++k) pk |= ((k < cur) ? mbuf[k] : 0xFF) << (8 * k);
                d_gp[G * 2] = pk; d_gp[G * 2 + 1] = t; ++G;
            }
        }
        // pad to exactly NG groups (G <= (128+3*16)/4 = 44 < 48 always)
        while (G < NG) { d_gp[G * 2] = (int)0xFFFFFFFF; d_gp[G * 2 + 1] = 0; ++G; }
    }
}

__global__ __launch_bounds__(512, 4)
void graph_linear_main(const float* __restrict__ input,   // [B,128,64] f32
                       const float* __restrict__ bias,    // [64] f32
                       float* __restrict__ out)           // [B,128,64] f32
{
    // h: [b=4][o=64][m=128] bf16 = 64 KiB; m XOR-swizzled by ((o&7)<<3) (short units).
    __shared__ short hbuf[BT * DOUT * NN];

    const int tid  = threadIdx.x;
    const int lane = tid & 63;
    const int wave = tid >> 6;        // 0..7
    const int lo   = lane & 15;
    const int hi   = lane >> 4;       // 0..3
    const int b0   = blockIdx.x * BT;

    // ---------------- stage 1: grouped MFMA, A rows r = mi*4 + bi ----------------
    // 6 compile-time iterations; compiler is free to hoist/interleave loads across
    // iterations (software-pipeline). No manual prefetch, no runtime branches.
    const int sl = lo >> 2;           // this lane's A-row m-slot
    const float* const inpb = input + (size_t)(b0 + (lo & 3)) * NN * DI;
    const int wbase = __builtin_amdgcn_readfirstlane(wave);

#pragma unroll
    for (int it = 0; it < NG / 8; ++it) {
        const int gi = (it * 8 + wbase) * 2;      // wave-uniform -> s_load
        const int pk = d_gp[gi];
        const int t  = d_gp[gi + 1];

        const int mA  = (pk >> (8 * sl)) & 0xFF;
        const int mAe = (mA == 0xFF) ? (pk & 0x7F) : mA;   // pad aliases a valid row
        const float* ip = inpb + mAe * DI + hi * 8;
        const f32x4 r0 = *(const f32x4*)(ip);
        const f32x4 r1 = *(const f32x4*)(ip + 4);
        const f32x4 r2 = *(const f32x4*)(ip + 32);
        const f32x4 r3 = *(const f32x4*)(ip + 36);
        const bf16x8 a0 = cvt8(r0, r1);           // k = 0..31
        const bf16x8 a1 = cvt8(r2, r3);           // k = 32..63

        const short* wrow = d_wb + t * (DOUT * DI);
        f32x4 hacc[4];
#pragma unroll
        for (int ot = 0; ot < 4; ++ot) hacc[ot] = 0.0f;
#pragma unroll
        for (int ot = 0; ot < 4; ++ot) {
            const int o = ot * 16 + lo;           // B-frag col
            const bf16x8 w0 = *(const bf16x8*)(wrow + o * DI + hi * 8);
            hacc[ot] = __builtin_amdgcn_mfma_f32_16x16x32_bf16(a0, w0, hacc[ot], 0, 0, 0);
            const bf16x8 w1 = *(const bf16x8*)(wrow + o * DI + 32 + hi * 8);
            hacc[ot] = __builtin_amdgcn_mfma_f32_16x16x32_bf16(a1, w1, hacc[ot], 0, 0, 0);
        }
        // D: col(o)=lane&15, row r=hi*4+j -> m-slot=hi, b=j
        const int mS = (pk >> (8 * hi)) & 0xFF;
        if (mS != 0xFF) {
#pragma unroll
            for (int ot = 0; ot < 4; ++ot) {
                const int o = ot * 16 + lo;
                const int p = mS ^ ((o & 7) << 3);
#pragma unroll
                for (int j = 0; j < 4; ++j)
                    hbuf[(j * DOUT + o) * NN + p] = f2bf(hacc[ot][j]);
            }
        }
    }
    __syncthreads();

    // ---------------- stage 2: wave -> (bi = w>>1, nh = w&1), streamed ----------------
    const int bi = wave >> 1;
    const int nh = wave & 1;
    const short* hrow = hbuf + bi * (DOUT * NN);
    const size_t outb = (size_t)(b0 + bi) * NN;

#pragma unroll
    for (int nt = 0; nt < 4; ++nt) {
        const int n = nh * 64 + nt * 16 + lo;              // B-frag col = n
        f32x4 acc[4];
#pragma unroll
        for (int ot = 0; ot < 4; ++ot)
            acc[ot] = *(const f32x4*)(bias + ot * 16 + hi * 4);   // bias pre-added
#pragma unroll
        for (int c = 0; c < 4; ++c) {
            const bf16x8 gfr = *(const bf16x8*)(d_gb + n * NN + c * 32 + hi * 8);
#pragma unroll
            for (int ot = 0; ot < 4; ++ot) {
                const int o   = ot * 16 + lo;              // A-frag row = o
                const int pos = (c * 32 + hi * 8) ^ ((o & 7) << 3);
                const bf16x8 hfr = *(const bf16x8*)&hrow[o * NN + pos];
                acc[ot] = __builtin_amdgcn_mfma_f32_16x16x32_bf16(hfr, gfr, acc[ot], 0, 0, 0);
            }
        }
        // D: col=lo -> n, row=hi*4+j -> o = ot*16+hi*4+j  => contiguous dwordx4
#pragma unroll
        for (int ot = 0; ot < 4; ++ot)
            *(f32x4*)&out[(outb + n) * DOUT + ot * 16 + hi * 4] = acc[ot];
    }
}

extern "C" void kernel_launch(void* const* d_in, const int* in_sizes, int n_in,
                              void* d_out, int out_size, void* d_ws, size_t ws_size,
                              hipStream_t stream) {
    const float* input  = (const float*)d_in[0];
    const float* g      = (const float*)d_in[1];
    const float* weight = (const float*)d_in[2];
    const float* bias   = (const float*)d_in[3];
    const int*   ntype  = (const int*)d_in[4];
    float* out = (float*)d_out;

    const int B = in_sizes[0] / (NN * DI);   // 16384

    hipLaunchKernelGGL(prep_kernel, dim3(32), dim3(256), 0, stream, weight, g, ntype);
    hipLaunchKernelGGL(graph_linear_main, dim3(B / BT), dim3(512), 0, stream,
                       input, bias, out);
}

// Round 8
// 427.737 us; speedup vs baseline: 1.2380x; 1.1507x over previous
//
#include <hip/hip_runtime.h>

// GraphLinear: out[b,n,o] = sum_m g[n,m] * (sum_i input[b,m,i]*W[type[m],o,i]) + bias[o]
// B=16384, N=128, DIN=DOUT=64, T=16.
// prep: bf16-convert weight/g (all blocks); block 0 builds groups of 8 same-type m's
//       in parallel (per-type lane scan). Partial groups padded with the group's own
//       first member; empty slots replicate a real group => all pad work is IDEMPOTENT
//       (duplicate writes carry identical values) => main kernel is branch-free.
// main: BT=2 b-rows/block, 512 threads (8 waves), 64 KiB LDS, 2 blocks/CU.
//   Phase 0: bulk copy input -> ibuf (bf16, i XOR-swizzled by m) - contiguous streaming,
//            8 independent dwordx4/thread so the compiler pipelines deeply.
//   Phase 1: branch-free grouped MFMA (8 m x 2 b share one W[t]); A from LDS, W from L2.
//   Phase 2: R5/R7 stage-2: streamed 16x16x32, A=h^T B=g^T, contiguous dwordx4 stores.

#define NN    128
#define DI    64
#define DOUT  64
#define BT    2
#define TT    16
#define NG    32   // padded group count (Σ⌈n_t/8⌉ <= 30 < 32 always)

typedef __attribute__((ext_vector_type(4))) float f32x4;
typedef __attribute__((ext_vector_type(8))) short bf16x8;
typedef __attribute__((ext_vector_type(4))) short bf16x4;

__device__ __forceinline__ short f2bf(float f) {
    unsigned u = __builtin_bit_cast(unsigned, f);
    u += 0x7FFFu + ((u >> 16) & 1u);   // round-to-nearest-even
    return (short)(u >> 16);
}

// Device-global scratch (rewritten every launch by prep_kernel; deterministic).
__device__ short d_wb[TT * DOUT * DI];   // bf16 weight [t][o][i], 128 KB (L2-hot)
__device__ short d_gb[NN * NN];          // bf16 g [n][m], 32 KB
__device__ int   d_gp[NG * 4];           // {m0..3 packed, m4..7 packed, type, 0}

__global__ void prep_kernel(const float* __restrict__ weight,
                            const float* __restrict__ g,
                            const int*   __restrict__ ntype) {
    const int tid    = blockIdx.x * blockDim.x + threadIdx.x;
    const int stride = gridDim.x * blockDim.x;
    for (int i = tid; i < TT * DOUT * DI; i += stride) d_wb[i] = f2bf(weight[i]);
    for (int i = tid; i < NN * NN; i += stride)        d_gb[i] = f2bf(g[i]);

    if (blockIdx.x == 0) {
        __shared__ int sh_t[NN];
        const int lt = threadIdx.x;
        if (lt < NN) sh_t[lt] = ntype[lt];
        __syncthreads();
        if (lt < TT) {   // lanes 0..15 of wave 0
            // count my type's nodes + remember first member
            int cnt = 0, m0 = 0;
            for (int m = NN - 1; m >= 0; --m)
                if (sh_t[m] == lt) { ++cnt; m0 = m; }
            const int ng = (cnt + 7) >> 3;
            // exclusive prefix + total over the 16 lanes
            int pfx = 0, total = 0;
            for (int t2 = 0; t2 < TT; ++t2) {
                const int v = __shfl(ng, t2, 64);
                if (t2 < lt) pfx += v;
                total += v;
            }
            // emit my groups; pad bytes pre-filled with m0 (idempotent duplicates)
            const int fill = m0 * 0x01010101;
            int Gw = pfx, cur = 0, p0 = fill, p1 = fill;
            int g0p0 = fill, g0p1 = fill, saved = 0;
            for (int m = 0; m < NN; ++m) {
                if (sh_t[m] == lt) {
                    if (cur < 4) p0 = (p0 & ~(0xFF << (8 * cur))) | (m << (8 * cur));
                    else         p1 = (p1 & ~(0xFF << (8 * (cur - 4)))) | (m << (8 * (cur - 4)));
                    if (++cur == 8) {
                        d_gp[Gw * 4 + 0] = p0; d_gp[Gw * 4 + 1] = p1;
                        d_gp[Gw * 4 + 2] = lt; d_gp[Gw * 4 + 3] = 0;
                        if (!saved) { g0p0 = p0; g0p1 = p1; saved = 1; }
                        ++Gw; cur = 0; p0 = fill; p1 = fill;
                    }
                }
            }
            if (cur > 0) {
                d_gp[Gw * 4 + 0] = p0; d_gp[Gw * 4 + 1] = p1;
                d_gp[Gw * 4 + 2] = lt; d_gp[Gw * 4 + 3] = 0;
                if (!saved) { g0p0 = p0; g0p1 = p1; saved = 1; }
                ++Gw;
            }
            // replicate one real group into the empty tail (idempotent padding)
            const unsigned long long msk = __ballot(ng > 0);
            const int srclane = __ffsll(msk) - 1;
            if (lt == srclane) {
                for (int gp = total; gp < NG; ++gp) {
                    d_gp[gp * 4 + 0] = g0p0; d_gp[gp * 4 + 1] = g0p1;
                    d_gp[gp * 4 + 2] = lt;   d_gp[gp * 4 + 3] = 0;
                }
            }
        }
    }
}

__global__ __launch_bounds__(512, 4)
void graph_linear_main(const float* __restrict__ input,   // [B,128,64] f32
                       const float* __restrict__ bias,    // [64] f32
                       float* __restrict__ out)           // [B,128,64] f32
{
    __shared__ short ibuf[BT * NN * DI];    // [b][m][i ^ ((m&7)<<3)] bf16, 32 KiB
    __shared__ short hbuf[BT * DOUT * NN];  // [b][o][m ^ ((o&7)<<3)] bf16, 32 KiB

    const int tid  = threadIdx.x;
    const int lane = tid & 63;
    const int wave = tid >> 6;        // 0..7
    const int lo   = lane & 15;
    const int hi   = lane >> 4;       // 0..3
    const int b0   = blockIdx.x * BT;

    // ---- phase 0: copy input -> ibuf (bf16, swizzled). 8 independent dwordx4/thread ----
    {
        const float* src = input + (size_t)b0 * (NN * DI);
#pragma unroll
        for (int q = 0; q < 8; ++q) {
            const int u  = q * 512 + tid;          // f32x4 unit, 4096 total
            const f32x4 v = *(const f32x4*)(src + u * 4);
            const int b  = u >> 11;
            const int m  = (u >> 4) & 127;
            const int i4 = (u & 15) << 2;
            bf16x4 w;
            w[0] = f2bf(v[0]); w[1] = f2bf(v[1]); w[2] = f2bf(v[2]); w[3] = f2bf(v[3]);
            *(bf16x4*)&ibuf[(b * NN + m) * DI + (i4 ^ ((m & 7) << 3))] = w;
        }
    }
    __syncthreads();

    // ---- phase 1: grouped MFMA, branch-free single BB ----
    // A rows r = lane&15 -> (mi = r>>1, bi = r&1); 4 groups/wave, interleaved.
    const int mi = lo >> 1;
    const int bA = lo & 1;
    const int wu = __builtin_amdgcn_readfirstlane(wave);

#pragma unroll
    for (int it = 0; it < NG / 8; ++it) {
        const int gidx = it * 8 + wu;
        const int pk0 = d_gp[gidx * 4 + 0];
        const int pk1 = d_gp[gidx * 4 + 1];
        const int t   = d_gp[gidx * 4 + 2];

        const int mA  = ((mi < 4 ? pk0 : pk1) >> ((mi & 3) * 8)) & 0xFF;
        const short* arow = &ibuf[(bA * NN + mA) * DI];
        const int swA = (mA & 7) << 3;
        const bf16x8 a0 = *(const bf16x8*)&arow[(hi * 8) ^ swA];         // k 0..31
        const bf16x8 a1 = *(const bf16x8*)&arow[(32 + hi * 8) ^ swA];    // k 32..63

        const short* wrow = d_wb + t * (DOUT * DI);
        f32x4 hacc[4];
#pragma unroll
        for (int ot = 0; ot < 4; ++ot) hacc[ot] = 0.0f;
#pragma unroll
        for (int ot = 0; ot < 4; ++ot) {
            const int o = ot * 16 + lo;                 // B-frag col
            const bf16x8 w0 = *(const bf16x8*)(wrow + o * DI + hi * 8);
            hacc[ot] = __builtin_amdgcn_mfma_f32_16x16x32_bf16(a0, w0, hacc[ot], 0, 0, 0);
            const bf16x8 w1 = *(const bf16x8*)(wrow + o * DI + 32 + hi * 8);
            hacc[ot] = __builtin_amdgcn_mfma_f32_16x16x32_bf16(a1, w1, hacc[ot], 0, 0, 0);
        }
        // D rows r = hi*4+j -> m-slot = hi*2 + (j>>1), b = j&1. Duplicates idempotent.
        const int mS0 = ((hi < 2 ? pk0 : pk1) >> (((hi * 2) & 3) * 8)) & 0xFF;
        const int mS1 = ((hi < 2 ? pk0 : pk1) >> (((hi * 2 + 1) & 3) * 8)) & 0xFF;
#pragma unroll
        for (int ot = 0; ot < 4; ++ot) {
            const int o   = ot * 16 + lo;
            const int swz = (o & 7) << 3;
            hbuf[(0 * DOUT + o) * NN + (mS0 ^ swz)] = f2bf(hacc[ot][0]);
            hbuf[(1 * DOUT + o) * NN + (mS0 ^ swz)] = f2bf(hacc[ot][1]);
            hbuf[(0 * DOUT + o) * NN + (mS1 ^ swz)] = f2bf(hacc[ot][2]);
            hbuf[(1 * DOUT + o) * NN + (mS1 ^ swz)] = f2bf(hacc[ot][3]);
        }
    }
    __syncthreads();

    // ---- phase 2: wave -> (bi = w&1, nq = w>>1), streamed 16x16x32 ----
    const int bi = wave & 1;
    const int nq = wave >> 1;                     // 0..3, 32 n each
    const short* hrow = hbuf + bi * (DOUT * NN);
    const size_t outb = (size_t)(b0 + bi) * NN;

#pragma unroll
    for (int nt = 0; nt < 2; ++nt) {
        const int n = nq * 32 + nt * 16 + lo;     // B-frag col = n
        f32x4 acc[4];
#pragma unroll
        for (int ot = 0; ot < 4; ++ot)
            acc[ot] = *(const f32x4*)(bias + ot * 16 + hi * 4);   // bias pre-added
#pragma unroll
        for (int c = 0; c < 4; ++c) {
            const bf16x8 gfr = *(const bf16x8*)(d_gb + n * NN + c * 32 + hi * 8);
#pragma unroll
            for (int ot = 0; ot < 4; ++ot) {
                const int o   = ot * 16 + lo;     // A-frag row = o
                const int pos = (c * 32 + hi * 8) ^ ((o & 7) << 3);
                const bf16x8 hfr = *(const bf16x8*)&hrow[o * NN + pos];
                acc[ot] = __builtin_amdgcn_mfma_f32_16x16x32_bf16(hfr, gfr, acc[ot], 0, 0, 0);
            }
        }
        // D: col=lo -> n, row=hi*4+j -> o = ot*16+hi*4+j  => contiguous dwordx4
#pragma unroll
        for (int ot = 0; ot < 4; ++ot)
            *(f32x4*)&out[(outb + n) * DOUT + ot * 16 + hi * 4] = acc[ot];
    }
}

extern "C" void kernel_launch(void* const* d_in, const int* in_sizes, int n_in,
                              void* d_out, int out_size, void* d_ws, size_t ws_size,
                              hipStream_t stream) {
    const float* input  = (const float*)d_in[0];
    const float* g      = (const float*)d_in[1];
    const float* weight = (const float*)d_in[2];
    const float* bias   = (const float*)d_in[3];
    const int*   ntype  = (const int*)d_in[4];
    float* out = (float*)d_out;

    const int B = in_sizes[0] / (NN * DI);   // 16384

    hipLaunchKernelGGL(prep_kernel, dim3(32), dim3(256), 0, stream, weight, g, ntype);
    hipLaunchKernelGGL(graph_linear_main, dim3(B / BT), dim3(512), 0, stream,
                       input, bias, out);
}